// Round 5
// baseline (3518.388 us; speedup 1.0000x reference)
//
#include <hip/hip_runtime.h>
#include <math.h>

// MySimpleRNN on MI355X — fp16 hi/lo split MFMA, software-pipelined B stream.
// h = tanh(x_t@wx + b + h@wh), 64 steps, B=4096, NF=128, NH=512.
//
// R5 = R4 with the pipeline data-hazard fixed: B(kb+2) prefetch now comes
// AFTER the MFMAs that consume B(kb) in source order (R4 clobbered the
// buffer before consuming it -> absmax 1.98). Compiler still hoists the
// loads early via SSA renaming; source order only pins the dataflow.
//
//  - 8 waves (512 thr), nt=4 col-tiles/wave; launch_bounds(512,2)
//  - unified 20-block K pipeline (4 wx-kb + 16 wh-kb), depth-2 register
//    double-buffer on the L2 B-fragment stream, depth-1 A prefetch from LDS
//  - conflict-free A-read layout: LDH=536 halfs, LDX=152
//  - fast tanh via __expf (exact +-1 saturation at extremes)
// Precision: 3 MFMA products (hi*hi + lo*hi + hi*lo) ~ fp32-level noise.
//
// mfma_f32_16x16x32_f16 layouts (learn_hip m89/m91/m120):
//   A: lane holds A[m=lane&15][k=(lane>>4)*8+j], j=0..7
//   B: lane holds B[k=(lane>>4)*8+j][n=lane&15]
//   C/D: reg r holds C[row=(lane>>4)*4+r][col=lane&15]

#define T_STEPS 64
#define NFD     128
#define NHD     512
#define BR      16
#define THREADS 512
#define NKB     20           // 4 wx k-blocks + 16 wh k-blocks
#define LDH     536          // fp16 row stride: 1072 B, 16B aligned
#define LDX     152          // 304 B, 16B aligned

typedef _Float16 half8 __attribute__((ext_vector_type(8)));
typedef _Float16 half4v __attribute__((ext_vector_type(4)));
typedef float float4v __attribute__((ext_vector_type(4)));

// ---- prep: split weights into fp16 hi/lo, pack combined fragment-linear ----
// table idx = ((ct*20 + kb)*64 + lane)*8 + j
//   kb 0..3  -> wx[(kb*32 + (lane>>4)*8 + j)*512 + ct*16 + (lane&15)]
//   kb 4..19 -> wh[((kb-4)*32 + (lane>>4)*8 + j)*512 + ct*16 + (lane&15)]
__global__ __launch_bounds__(256) void rnn_prep(
    const float* __restrict__ wh, const float* __restrict__ wx,
    _Float16* __restrict__ tbl_hi, _Float16* __restrict__ tbl_lo)
{
    int idx = blockIdx.x * 256 + threadIdx.x;     // 0 .. 327679
    int j   = idx & 7;
    int l   = (idx >> 3) & 63;
    int rem = idx >> 9;                           // 0..639
    int kb  = rem % 20;
    int ct  = rem / 20;                           // 0..31
    int n   = ct * 16 + (l & 15);
    int kq  = (l >> 4) * 8 + j;
    float v;
    if (kb < 4) v = wx[(kb * 32 + kq) * NHD + n];
    else        v = wh[((kb - 4) * 32 + kq) * NHD + n];
    _Float16 hi = (_Float16)v;
    tbl_hi[idx] = hi;
    tbl_lo[idx] = (_Float16)(v - (float)hi);
}

__device__ __forceinline__ float fast_tanh(float v) {
    float e = __expf(2.0f * v);          // inf/0 saturate cleanly to +-1
    return 1.0f - 2.0f / (e + 1.0f);
}

// ---- main fused recurrence ----
__global__ __launch_bounds__(THREADS, 2) void rnn_mfma(
    const float* __restrict__ x,
    const float* __restrict__ bias,
    const _Float16* __restrict__ tbl_hi, const _Float16* __restrict__ tbl_lo,
    float* __restrict__ out)
{
    __shared__ _Float16 sh_hhi[BR * LDH];
    __shared__ _Float16 sh_hlo[BR * LDH];
    __shared__ _Float16 sh_xhi[BR * LDX];
    __shared__ _Float16 sh_xlo[BR * LDX];

    const int tid  = (int)threadIdx.x;
    const int lane = tid & 63;
    const int w    = tid >> 6;        // wave 0..7
    const int ct0  = w * 4;           // this wave's 4 col-tiles
    const int m    = lane & 15;
    const int quad = lane >> 4;
    const int row0 = (int)blockIdx.x * BR;

    for (int i = tid; i < BR * LDH; i += THREADS) {
        sh_hhi[i] = (_Float16)0.f;
        sh_hlo[i] = (_Float16)0.f;
    }

    float bv[4];
    #pragma unroll
    for (int nt = 0; nt < 4; ++nt) bv[nt] = bias[(ct0 + nt) * 16 + m];

    // x staging: 512 threads cover 16 rows x 128 floats, 4 floats each
    const int xrow = tid >> 5;         // 0..15
    const int xcol = (tid & 31) * 4;   // 0..124
    const float* xptr = x + (row0 + xrow) * (T_STEPS * NFD) + xcol;
    float4 px = *(const float4*)xptr;

    const half8* th = (const half8*)tbl_hi;
    const half8* tl = (const half8*)tbl_lo;

    // register pipeline state
    half8 bh[2][4], bl[2][4];          // B double buffer (prefetch distance 2)
    half8 ah[2], al[2];                // A double buffer (prefetch distance 1)

    for (int t = 0; t < T_STEPS; ++t) {
        // stage x(t): fp32 -> fp16 hi/lo
        {
            half4v vh, vl;
            float xs[4] = {px.x, px.y, px.z, px.w};
            #pragma unroll
            for (int j = 0; j < 4; ++j) {
                _Float16 hi = (_Float16)xs[j];
                vh[j] = hi;
                vl[j] = (_Float16)(xs[j] - (float)hi);
            }
            *(half4v*)&sh_xhi[xrow * LDX + xcol] = vh;
            *(half4v*)&sh_xlo[xrow * LDX + xcol] = vl;
        }

        // issue B(0), B(1) loads before the barrier; they complete during it
        #pragma unroll
        for (int nt = 0; nt < 4; ++nt) {
            int fi0 = ((ct0 + nt) * NKB + 0) * 64 + lane;
            int fi1 = ((ct0 + nt) * NKB + 1) * 64 + lane;
            bh[0][nt] = th[fi0]; bl[0][nt] = tl[fi0];
            bh[1][nt] = th[fi1]; bl[1][nt] = tl[fi1];
        }

        __syncthreads();   // x(t) staged; h(t-1) writes visible

        if (t + 1 < T_STEPS) px = *(const float4*)(xptr + (t + 1) * NFD);

        float4v acc[4];
        #pragma unroll
        for (int nt = 0; nt < 4; ++nt) {
            acc[nt][0] = bv[nt]; acc[nt][1] = bv[nt];
            acc[nt][2] = bv[nt]; acc[nt][3] = bv[nt];
        }

        // A(0) from sh_x
        ah[0] = *(const half8*)&sh_xhi[m * LDX + quad * 8];
        al[0] = *(const half8*)&sh_xlo[m * LDX + quad * 8];

        // unified K pipeline: kb 0..3 = wx (A from sh_x), kb 4..19 = wh (A from sh_h)
        #pragma unroll
        for (int kb = 0; kb < NKB; ++kb) {
            const int cur = kb & 1, nxt = cur ^ 1;

            // prefetch A(kb+1) from LDS (writes a[nxt], reads nothing we consume now)
            if (kb + 1 < NKB) {
                const int ka = kb + 1;
                if (ka < 4) {
                    ah[nxt] = *(const half8*)&sh_xhi[m * LDX + ka * 32 + quad * 8];
                    al[nxt] = *(const half8*)&sh_xlo[m * LDX + ka * 32 + quad * 8];
                } else {
                    ah[nxt] = *(const half8*)&sh_hhi[m * LDH + (ka - 4) * 32 + quad * 8];
                    al[nxt] = *(const half8*)&sh_hlo[m * LDH + (ka - 4) * 32 + quad * 8];
                }
            }

            // 12 MFMAs consuming A(kb), B(kb) — BEFORE the b[cur] overwrite below
            #pragma unroll
            for (int nt = 0; nt < 4; ++nt) {
                acc[nt] = __builtin_amdgcn_mfma_f32_16x16x32_f16(ah[cur], bh[cur][nt], acc[nt], 0, 0, 0);
                acc[nt] = __builtin_amdgcn_mfma_f32_16x16x32_f16(al[cur], bh[cur][nt], acc[nt], 0, 0, 0);
                acc[nt] = __builtin_amdgcn_mfma_f32_16x16x32_f16(ah[cur], bl[cur][nt], acc[nt], 0, 0, 0);
            }

            // NOW refill the just-consumed buffer with B(kb+2) (consumed at iter kb+2)
            if (kb + 2 < NKB) {
                #pragma unroll
                for (int nt = 0; nt < 4; ++nt) {
                    int fi = ((ct0 + nt) * NKB + kb + 2) * 64 + lane;
                    bh[cur][nt] = th[fi];
                    bl[cur][nt] = tl[fi];
                }
            }
        }

        __syncthreads();   // all sh_h / sh_x reads for step t complete

        // epilogue (C/D: row=quad*4+r, col=(ct0+nt)*16+m)
        if (t == T_STEPS - 1) {
            #pragma unroll
            for (int nt = 0; nt < 4; ++nt)
                #pragma unroll
                for (int r = 0; r < 4; ++r)
                    out[(row0 + quad * 4 + r) * NHD + (ct0 + nt) * 16 + m] = fast_tanh(acc[nt][r]);
        } else {
            #pragma unroll
            for (int nt = 0; nt < 4; ++nt) {
                #pragma unroll
                for (int r = 0; r < 4; ++r) {
                    float v = fast_tanh(acc[nt][r]);
                    _Float16 hi = (_Float16)v;
                    int off = (quad * 4 + r) * LDH + (ct0 + nt) * 16 + m;
                    sh_hhi[off] = hi;
                    sh_hlo[off] = (_Float16)(v - (float)hi);
                }
            }
        }
    }
}

extern "C" void kernel_launch(void* const* d_in, const int* in_sizes, int n_in,
                              void* d_out, int out_size, void* d_ws, size_t ws_size,
                              hipStream_t stream) {
    const float* x    = (const float*)d_in[0];  // [B, 64, 128]
    const float* wx   = (const float*)d_in[1];  // [128, 512]
    const float* wh   = (const float*)d_in[2];  // [512, 512]
    const float* bias = (const float*)d_in[3];  // [512]
    float* out = (float*)d_out;                 // [B, 512]

    // workspace: tbl_hi 640KB | tbl_lo 640KB (combined wx+wh fragment tables)
    char* ws = (char*)d_ws;
    _Float16* tbl_hi = (_Float16*)(ws);
    _Float16* tbl_lo = (_Float16*)(ws + 655360);

    rnn_prep<<<1280, 256, 0, stream>>>(wh, wx, tbl_hi, tbl_lo);

    const int B = in_sizes[0] / (T_STEPS * NFD);   // 4096
    rnn_mfma<<<B / BR, THREADS, 0, stream>>>(x, bias, tbl_hi, tbl_lo, out);
}

// Round 6
// 2306.648 us; speedup vs baseline: 1.5253x; 1.5253x over previous
//
#include <hip/hip_runtime.h>
#include <math.h>

// MySimpleRNN on MI355X — fp16 hi/lo split MFMA.
// h = tanh(x_t@wx + b + h@wh), 64 steps, B=4096, NF=128, NH=512.
//
// R6 design (post-mortems R3/R5):
//  - R5's dist-2 pipeline spilled (live set > 128 VGPR): FETCH 7.3GB of
//    scratch traffic, L2 polluted, 3.5ms. R3's 16-wave idea was right but
//    launch_bounds(1024,4) capped VGPR at 64 (arg2 acts like min-BLOCKS/CU,
//    CUDA-style: (512,2)->128, (1024,4)->64 observed) -> spills.
//  - This round: 16 waves (1024 thr, single-arg launch_bounds -> cap 128),
//    nt=2 col-tiles/wave, 4 waves/SIMD latency hiding, dist-1 double-buffer
//    (hazard-free: write b[nxt] while consuming b[cur]); live set ~90 VGPR.
//  - hi/lo fragments interleaved in one table: 32 B contiguous per lane
//    per (ct,kb) -> two dwordx4 from one address.
//  - conflict-free A-read layout LDH=536 (16B-granule pos = (3m+quad)%8,
//    uniform 8 lanes/position), LDX=152.
// Precision: 3 MFMA products (hi*hi + lo*hi + hi*lo) ~ fp32-level noise;
// measured absmax 0.0039 (= comparison quantum) in R2/R5.
//
// mfma_f32_16x16x32_f16 layouts (learn_hip m89/m91/m120):
//   A: lane holds A[m=lane&15][k=(lane>>4)*8+j], j=0..7
//   B: lane holds B[k=(lane>>4)*8+j][n=lane&15]
//   C/D: reg r holds C[row=(lane>>4)*4+r][col=lane&15]

#define T_STEPS 64
#define NFD     128
#define NHD     512
#define BR      16
#define THREADS 1024
#define NT      2            // col-tiles per wave (16 waves x 2 = 32 tiles)
#define NKB     20           // 4 wx k-blocks + 16 wh k-blocks
#define LDH     536          // fp16 row stride: 1072 B
#define LDX     152          // 304 B

typedef _Float16 half8 __attribute__((ext_vector_type(8)));
typedef _Float16 half2v __attribute__((ext_vector_type(2)));
typedef float float4v __attribute__((ext_vector_type(4)));

// ---- prep: split weights into fp16 hi/lo, pack fragment-linear, hi/lo
// interleaved: tbl halfs [((ct*20 + kb)*64 + lane)*16 + (j | 8+j)]
//   kb 0..3  -> wx[(kb*32 + (lane>>4)*8 + j)*512 + ct*16 + (lane&15)]
//   kb 4..19 -> wh[((kb-4)*32 + (lane>>4)*8 + j)*512 + ct*16 + (lane&15)]
__global__ __launch_bounds__(256) void rnn_prep(
    const float* __restrict__ wh, const float* __restrict__ wx,
    _Float16* __restrict__ tbl)
{
    int idx = blockIdx.x * 256 + threadIdx.x;     // 0 .. 327679
    int j   = idx & 7;
    int l   = (idx >> 3) & 63;
    int rem = idx >> 9;                           // 0..639
    int kb  = rem % 20;
    int ct  = rem / 20;                           // 0..31
    int n   = ct * 16 + (l & 15);
    int kq  = (l >> 4) * 8 + j;
    float v;
    if (kb < 4) v = wx[(kb * 32 + kq) * NHD + n];
    else        v = wh[((kb - 4) * 32 + kq) * NHD + n];
    _Float16 hi = (_Float16)v;
    int base = ((ct * NKB + kb) * 64 + l) * 16;
    tbl[base + j]     = hi;
    tbl[base + 8 + j] = (_Float16)(v - (float)hi);
}

__device__ __forceinline__ float fast_tanh(float v) {
    float e = __expf(2.0f * v);          // inf/0 saturate cleanly to +-1
    return 1.0f - 2.0f / (e + 1.0f);
}

// ---- main fused recurrence ----
__global__ __launch_bounds__(THREADS) void rnn_mfma(
    const float* __restrict__ x,
    const float* __restrict__ bias,
    const _Float16* __restrict__ tbl,
    float* __restrict__ out)
{
    __shared__ _Float16 sh_hhi[BR * LDH];
    __shared__ _Float16 sh_hlo[BR * LDH];
    __shared__ _Float16 sh_xhi[BR * LDX];
    __shared__ _Float16 sh_xlo[BR * LDX];

    const int tid  = (int)threadIdx.x;
    const int lane = tid & 63;
    const int w    = tid >> 6;        // wave 0..15
    const int ct0  = w * NT;          // this wave's col-tiles
    const int m    = lane & 15;
    const int quad = lane >> 4;
    const int row0 = (int)blockIdx.x * BR;

    for (int i = tid; i < BR * LDH; i += THREADS) {
        sh_hhi[i] = (_Float16)0.f;
        sh_hlo[i] = (_Float16)0.f;
    }

    float bv[NT];
    #pragma unroll
    for (int nt = 0; nt < NT; ++nt) bv[nt] = bias[(ct0 + nt) * 16 + m];

    // x staging: 1024 threads cover 16 rows x 128 floats, 2 floats each
    const int xrow = tid >> 6;         // 0..15
    const int xcol = (tid & 63) * 2;   // 0..126
    const float* xptr = x + (row0 + xrow) * (T_STEPS * NFD) + xcol;
    float2 px = *(const float2*)xptr;

    // per-wave fragment pointer: (ct,kb) pair base in half8 units
    const half8* tb = (const half8*)tbl + lane * 2;

    half8 bh[2][NT], bl[2][NT];        // B double buffer, dist-1
    half8 ah[2], al[2];                // A double buffer, dist-1

    for (int t = 0; t < T_STEPS; ++t) {
        // stage x(t): fp32 -> fp16 hi/lo
        {
            half2v vh, vl;
            float xs[2] = {px.x, px.y};
            #pragma unroll
            for (int j = 0; j < 2; ++j) {
                _Float16 hi = (_Float16)xs[j];
                vh[j] = hi;
                vl[j] = (_Float16)(xs[j] - (float)hi);
            }
            *(half2v*)&sh_xhi[xrow * LDX + xcol] = vh;
            *(half2v*)&sh_xlo[xrow * LDX + xcol] = vl;
        }

        // preload B(kb=0) before the barrier (completes during it)
        #pragma unroll
        for (int nt = 0; nt < NT; ++nt) {
            const half8* p = tb + ((ct0 + nt) * NKB + 0) * 128;
            bh[0][nt] = p[0];
            bl[0][nt] = p[1];
        }

        __syncthreads();   // x(t) staged; h(t-1) writes visible

        if (t + 1 < T_STEPS) px = *(const float2*)(xptr + (t + 1) * NFD);

        float4v acc[NT];
        #pragma unroll
        for (int nt = 0; nt < NT; ++nt) {
            acc[nt][0] = bv[nt]; acc[nt][1] = bv[nt];
            acc[nt][2] = bv[nt]; acc[nt][3] = bv[nt];
        }

        // A(0) from sh_x
        ah[0] = *(const half8*)&sh_xhi[m * LDX + quad * 8];
        al[0] = *(const half8*)&sh_xlo[m * LDX + quad * 8];

        // unified K pipeline: kb 0..3 = wx (A from sh_x), 4..19 = wh (A from sh_h)
        #pragma unroll
        for (int kb = 0; kb < NKB; ++kb) {
            const int cur = kb & 1, nxt = cur ^ 1;

            // dist-1 prefetch into the OTHER buffer (no hazard with cur)
            if (kb + 1 < NKB) {
                const int ka = kb + 1;
                if (ka < 4) {
                    ah[nxt] = *(const half8*)&sh_xhi[m * LDX + ka * 32 + quad * 8];
                    al[nxt] = *(const half8*)&sh_xlo[m * LDX + ka * 32 + quad * 8];
                } else {
                    ah[nxt] = *(const half8*)&sh_hhi[m * LDH + (ka - 4) * 32 + quad * 8];
                    al[nxt] = *(const half8*)&sh_hlo[m * LDH + (ka - 4) * 32 + quad * 8];
                }
                #pragma unroll
                for (int nt = 0; nt < NT; ++nt) {
                    const half8* p = tb + ((ct0 + nt) * NKB + ka) * 128;
                    bh[nxt][nt] = p[0];
                    bl[nxt][nt] = p[1];
                }
            }

            // 6 MFMAs consuming A(kb), B(kb)
            #pragma unroll
            for (int nt = 0; nt < NT; ++nt) {
                acc[nt] = __builtin_amdgcn_mfma_f32_16x16x32_f16(ah[cur], bh[cur][nt], acc[nt], 0, 0, 0);
                acc[nt] = __builtin_amdgcn_mfma_f32_16x16x32_f16(al[cur], bh[cur][nt], acc[nt], 0, 0, 0);
                acc[nt] = __builtin_amdgcn_mfma_f32_16x16x32_f16(ah[cur], bl[cur][nt], acc[nt], 0, 0, 0);
            }
        }

        __syncthreads();   // all sh_h / sh_x reads for step t complete

        // epilogue (C/D: row=quad*4+r, col=(ct0+nt)*16+m)
        if (t == T_STEPS - 1) {
            #pragma unroll
            for (int nt = 0; nt < NT; ++nt)
                #pragma unroll
                for (int r = 0; r < 4; ++r)
                    out[(row0 + quad * 4 + r) * NHD + (ct0 + nt) * 16 + m] = fast_tanh(acc[nt][r]);
        } else {
            #pragma unroll
            for (int nt = 0; nt < NT; ++nt) {
                #pragma unroll
                for (int r = 0; r < 4; ++r) {
                    float v = fast_tanh(acc[nt][r]);
                    _Float16 hi = (_Float16)v;
                    int off = (quad * 4 + r) * LDH + (ct0 + nt) * 16 + m;
                    sh_hhi[off] = hi;
                    sh_hlo[off] = (_Float16)(v - (float)hi);
                }
            }
        }
    }
}

extern "C" void kernel_launch(void* const* d_in, const int* in_sizes, int n_in,
                              void* d_out, int out_size, void* d_ws, size_t ws_size,
                              hipStream_t stream) {
    const float* x    = (const float*)d_in[0];  // [B, 64, 128]
    const float* wx   = (const float*)d_in[1];  // [128, 512]
    const float* wh   = (const float*)d_in[2];  // [512, 512]
    const float* bias = (const float*)d_in[3];  // [512]
    float* out = (float*)d_out;                 // [B, 512]

    // workspace: tbl 1.25 MB (combined wx+wh fragment table, hi/lo interleaved)
    _Float16* tbl = (_Float16*)d_ws;

    rnn_prep<<<1280, 256, 0, stream>>>(wh, wx, tbl);

    const int B = in_sizes[0] / (T_STEPS * NFD);   // 4096
    rnn_mfma<<<B / BR, THREADS, 0, stream>>>(x, bias, tbl, out);
}

// Round 7
// 2240.191 us; speedup vs baseline: 1.5706x; 1.0297x over previous
//
#include <hip/hip_runtime.h>
#include <math.h>

// MySimpleRNN on MI355X — fp16 hi/lo split MFMA, BR=32 (grid=128).
// h = tanh(x_t@wx + b + h@wh), 64 steps, B=4096, NF=128, NH=512.
//
// R7 design (post-mortems R2..R6):
//  - HARD RULE learned: 1024-thr blocks force VGPR<=64 on gfx950 -> spills
//    (R3/R6: FETCH 7-8 GB scratch). 512-thr blocks get 128 VGPR (R2, clean).
//  - Bottleneck is the per-block weight-fragment stream from L2: 1.31 MB/step
//    per block, zero intra-block reuse. 256 blocks = 42 MB/step/XCD = 23.3k
//    cyc/step floor. BR=32 -> 128 blocks halves that: floor ~11.7k cyc/step
//    (~312 us). The 2nd M-tile rides the same B-fragments (free reuse);
//    MFMA (~4.7k cyc/step) stays far under the L2 floor.
//  - Register budget for the 128 cap: acc 2Mx4ntx4=32, B dist-1 double
//    buffer (hi+lo) 64, A just-in-time 16 -> ~112 live. A's LDS latency is
//    covered by 2 waves/SIMD + compiler lgkmcnt scheduling (m97 evidence).
// Precision: 3 MFMA products (hi*hi + lo*hi + hi*lo) ~ fp32-level noise;
// measured absmax 0.0039 (= comparison quantum) in R2/R5/R6.
//
// mfma_f32_16x16x32_f16 layouts (learn_hip m89/m91/m120):
//   A: lane holds A[m=lane&15][k=(lane>>4)*8+j], j=0..7
//   B: lane holds B[k=(lane>>4)*8+j][n=lane&15]
//   C/D: reg r holds C[row=(lane>>4)*4+r][col=lane&15]

#define T_STEPS 64
#define NFD     128
#define NHD     512
#define BR      32           // rows per block -> grid = 4096/32 = 128
#define THREADS 512          // 8 waves -> VGPR cap 128 (do NOT use 1024)
#define NT      4            // col-tiles per wave (8 waves x 4 = 32 tiles)
#define NM      2            // M-tiles per block (BR/16)
#define NKB     20           // 4 wx k-blocks + 16 wh k-blocks
#define LDH     536          // fp16 row stride: 1072 B (conflict-free b128 reads)
#define LDX     152          // 304 B

typedef _Float16 half8 __attribute__((ext_vector_type(8)));
typedef _Float16 half4v __attribute__((ext_vector_type(4)));
typedef float float4v __attribute__((ext_vector_type(4)));

// ---- prep: split weights into fp16 hi/lo, pack fragment-linear, hi/lo
// interleaved: tbl halfs [((ct*20 + kb)*64 + lane)*16 + (j | 8+j)]
//   kb 0..3  -> wx[(kb*32 + (lane>>4)*8 + j)*512 + ct*16 + (lane&15)]
//   kb 4..19 -> wh[((kb-4)*32 + (lane>>4)*8 + j)*512 + ct*16 + (lane&15)]
__global__ __launch_bounds__(256) void rnn_prep(
    const float* __restrict__ wh, const float* __restrict__ wx,
    _Float16* __restrict__ tbl)
{
    int idx = blockIdx.x * 256 + threadIdx.x;     // 0 .. 327679
    int j   = idx & 7;
    int l   = (idx >> 3) & 63;
    int rem = idx >> 9;                           // 0..639
    int kb  = rem % 20;
    int ct  = rem / 20;                           // 0..31
    int n   = ct * 16 + (l & 15);
    int kq  = (l >> 4) * 8 + j;
    float v;
    if (kb < 4) v = wx[(kb * 32 + kq) * NHD + n];
    else        v = wh[((kb - 4) * 32 + kq) * NHD + n];
    _Float16 hi = (_Float16)v;
    int base = ((ct * NKB + kb) * 64 + l) * 16;
    tbl[base + j]     = hi;
    tbl[base + 8 + j] = (_Float16)(v - (float)hi);
}

__device__ __forceinline__ float fast_tanh(float v) {
    float e = __expf(2.0f * v);          // inf/0 saturate cleanly to +-1
    return 1.0f - 2.0f / (e + 1.0f);
}

// ---- main fused recurrence ----
__global__ __launch_bounds__(THREADS) void rnn_mfma(
    const float* __restrict__ x,
    const float* __restrict__ bias,
    const _Float16* __restrict__ tbl,
    float* __restrict__ out)
{
    __shared__ _Float16 sh_hhi[BR * LDH];   // 33.5 KB
    __shared__ _Float16 sh_hlo[BR * LDH];   // 33.5 KB
    __shared__ _Float16 sh_xhi[BR * LDX];   // 9.5 KB
    __shared__ _Float16 sh_xlo[BR * LDX];   // 9.5 KB

    const int tid  = (int)threadIdx.x;
    const int lane = tid & 63;
    const int w    = tid >> 6;        // wave 0..7
    const int ct0  = w * NT;          // this wave's 4 col-tiles
    const int m    = lane & 15;
    const int quad = lane >> 4;
    const int row0 = (int)blockIdx.x * BR;

    for (int i = tid; i < BR * LDH; i += THREADS) {
        sh_hhi[i] = (_Float16)0.f;
        sh_hlo[i] = (_Float16)0.f;
    }

    float bv[NT];
    #pragma unroll
    for (int nt = 0; nt < NT; ++nt) bv[nt] = bias[(ct0 + nt) * 16 + m];

    // x staging: 512 threads cover 32 rows x 128 floats, 8 floats each
    const int xrow = tid >> 4;         // 0..31
    const int xcol = (tid & 15) * 8;   // 0..120
    const float* xptr = x + (row0 + xrow) * (T_STEPS * NFD) + xcol;
    float4 px0 = *(const float4*)xptr;
    float4 px1 = *(const float4*)(xptr + 4);

    // per-lane fragment table base (half8 units)
    const half8* tb = (const half8*)tbl + lane * 2;

    half8 bh[2][NT], bl[2][NT];        // B double buffer, dist-1 (64 VGPR)

    for (int t = 0; t < T_STEPS; ++t) {
        // stage x(t): fp32 -> fp16 hi/lo
        {
            half4v vh0, vl0, vh1, vl1;
            float xs[8] = {px0.x, px0.y, px0.z, px0.w, px1.x, px1.y, px1.z, px1.w};
            #pragma unroll
            for (int j = 0; j < 4; ++j) {
                _Float16 hi = (_Float16)xs[j];
                vh0[j] = hi;  vl0[j] = (_Float16)(xs[j] - (float)hi);
                _Float16 hj = (_Float16)xs[4 + j];
                vh1[j] = hj;  vl1[j] = (_Float16)(xs[4 + j] - (float)hj);
            }
            *(half4v*)&sh_xhi[xrow * LDX + xcol]     = vh0;
            *(half4v*)&sh_xhi[xrow * LDX + xcol + 4] = vh1;
            *(half4v*)&sh_xlo[xrow * LDX + xcol]     = vl0;
            *(half4v*)&sh_xlo[xrow * LDX + xcol + 4] = vl1;
        }

        // preload B(kb=0) before the barrier (completes during it)
        #pragma unroll
        for (int nt = 0; nt < NT; ++nt) {
            const half8* p = tb + ((ct0 + nt) * NKB + 0) * 128;
            bh[0][nt] = p[0];
            bl[0][nt] = p[1];
        }

        __syncthreads();   // x(t) staged; h(t-1) writes visible

        if (t + 1 < T_STEPS) {
            px0 = *(const float4*)(xptr + (t + 1) * NFD);
            px1 = *(const float4*)(xptr + (t + 1) * NFD + 4);
        }

        float4v acc[NM][NT];
        #pragma unroll
        for (int mi = 0; mi < NM; ++mi)
            #pragma unroll
            for (int nt = 0; nt < NT; ++nt) {
                acc[mi][nt][0] = bv[nt]; acc[mi][nt][1] = bv[nt];
                acc[mi][nt][2] = bv[nt]; acc[mi][nt][3] = bv[nt];
            }

        // unified K pipeline: kb 0..3 = wx (A from sh_x), 4..19 = wh (A from sh_h)
        #pragma unroll
        for (int kb = 0; kb < NKB; ++kb) {
            const int cur = kb & 1, nxt = cur ^ 1;

            // dist-1 B prefetch into the OTHER buffer (hazard-free)
            if (kb + 1 < NKB) {
                #pragma unroll
                for (int nt = 0; nt < NT; ++nt) {
                    const half8* p = tb + ((ct0 + nt) * NKB + kb + 1) * 128;
                    bh[nxt][nt] = p[0];
                    bl[nxt][nt] = p[1];
                }
            }

            // A fragments for both M-tiles, just-in-time from LDS
            half8 ahi[NM], alo[NM];
            if (kb < 4) {
                #pragma unroll
                for (int mi = 0; mi < NM; ++mi) {
                    ahi[mi] = *(const half8*)&sh_xhi[(mi * 16 + m) * LDX + kb * 32 + quad * 8];
                    alo[mi] = *(const half8*)&sh_xlo[(mi * 16 + m) * LDX + kb * 32 + quad * 8];
                }
            } else {
                #pragma unroll
                for (int mi = 0; mi < NM; ++mi) {
                    ahi[mi] = *(const half8*)&sh_hhi[(mi * 16 + m) * LDH + (kb - 4) * 32 + quad * 8];
                    alo[mi] = *(const half8*)&sh_hlo[(mi * 16 + m) * LDH + (kb - 4) * 32 + quad * 8];
                }
            }

            // 24 MFMAs: both M-tiles ride the same B fragments (the BR=32 win)
            #pragma unroll
            for (int mi = 0; mi < NM; ++mi)
                #pragma unroll
                for (int nt = 0; nt < NT; ++nt) {
                    acc[mi][nt] = __builtin_amdgcn_mfma_f32_16x16x32_f16(ahi[mi], bh[cur][nt], acc[mi][nt], 0, 0, 0);
                    acc[mi][nt] = __builtin_amdgcn_mfma_f32_16x16x32_f16(alo[mi], bh[cur][nt], acc[mi][nt], 0, 0, 0);
                    acc[mi][nt] = __builtin_amdgcn_mfma_f32_16x16x32_f16(ahi[mi], bl[cur][nt], acc[mi][nt], 0, 0, 0);
                }
        }

        __syncthreads();   // all sh_h / sh_x reads for step t complete

        // epilogue (C/D: row = mi*16 + quad*4 + r, col = (ct0+nt)*16 + m)
        if (t == T_STEPS - 1) {
            #pragma unroll
            for (int mi = 0; mi < NM; ++mi)
                #pragma unroll
                for (int nt = 0; nt < NT; ++nt)
                    #pragma unroll
                    for (int r = 0; r < 4; ++r)
                        out[(row0 + mi * 16 + quad * 4 + r) * NHD + (ct0 + nt) * 16 + m]
                            = fast_tanh(acc[mi][nt][r]);
        } else {
            #pragma unroll
            for (int mi = 0; mi < NM; ++mi)
                #pragma unroll
                for (int nt = 0; nt < NT; ++nt)
                    #pragma unroll
                    for (int r = 0; r < 4; ++r) {
                        float v = fast_tanh(acc[mi][nt][r]);
                        _Float16 hi = (_Float16)v;
                        int off = (mi * 16 + quad * 4 + r) * LDH + (ct0 + nt) * 16 + m;
                        sh_hhi[off] = hi;
                        sh_hlo[off] = (_Float16)(v - (float)hi);
                    }
        }
    }
}

extern "C" void kernel_launch(void* const* d_in, const int* in_sizes, int n_in,
                              void* d_out, int out_size, void* d_ws, size_t ws_size,
                              hipStream_t stream) {
    const float* x    = (const float*)d_in[0];  // [B, 64, 128]
    const float* wx   = (const float*)d_in[1];  // [128, 512]
    const float* wh   = (const float*)d_in[2];  // [512, 512]
    const float* bias = (const float*)d_in[3];  // [512]
    float* out = (float*)d_out;                 // [B, 512]

    // workspace: tbl 1.25 MB (combined wx+wh fragment table, hi/lo interleaved)
    _Float16* tbl = (_Float16*)d_ws;

    rnn_prep<<<1280, 256, 0, stream>>>(wh, wx, tbl);

    const int B = in_sizes[0] / (T_STEPS * NFD);   // 4096
    rnn_mfma<<<B / BR, THREADS, 0, stream>>>(x, bias, tbl, out);
}